// Round 1
// baseline (1475.049 us; speedup 1.0000x reference)
//
#include <hip/hip_runtime.h>

// ---------------------------------------------------------------------------
// MixedFPQuantizedLinear: per-32-block MXFP4 quant of x (fp16 scale) then
// C = x_q @ W^T + bias.  M=8192, K=4096, N=11008, all fp32 in/out.
// Strategy: quantize x -> fp16 (exact-enough: snapped*scale has <=13 mantissa
// bits, fp16 keeps 11), convert W -> fp16, then m97-style MFMA GEMM
// (128x128 tile, BK=32, global_load_lds width16, 16x16x32 f16 MFMA).
// ---------------------------------------------------------------------------

#define M_DIM 8192
#define K_DIM 4096
#define N_DIM 11008

typedef float floatx4 __attribute__((ext_vector_type(4)));
typedef _Float16 half8 __attribute__((ext_vector_type(8)));

// ----------------------------- quantization --------------------------------

__device__ inline float snap_mxfp4(float a) {
    // grid {0,0.5,1,1.5,2,3,4,6}; ties go to LOWER value (matches ref:
    // hi chosen only if a-lo > hi-a strictly).
    float lo  = (a <= 0.25f) ? 0.0f : ((a <= 0.75f) ? 0.5f : 1.0f);
    float mid = (a <= 1.75f) ? 1.5f : 2.0f;
    float hi  = (a <= 3.5f)  ? 3.0f : ((a <= 5.0f) ? 4.0f : 6.0f);
    return (a <= 1.25f) ? lo : ((a <= 2.5f) ? mid : hi);
}

// 8 elements per thread; 4 consecutive threads share one 32-elem quant block.
__global__ __launch_bounds__(256) void quant_x_kernel(
        const float* __restrict__ x, _Float16* __restrict__ xq) {
    size_t t    = (size_t)blockIdx.x * 256 + threadIdx.x;
    size_t base = t * 8;
    const float4* p = (const float4*)(x + base);
    float4 v0 = p[0];
    float4 v1 = p[1];
    float in[8] = {v0.x, v0.y, v0.z, v0.w, v1.x, v1.y, v1.z, v1.w};

    float a0 = fmaxf(fmaxf(fabsf(in[0]), fabsf(in[1])), fmaxf(fabsf(in[2]), fabsf(in[3])));
    float a1 = fmaxf(fmaxf(fabsf(in[4]), fabsf(in[5])), fmaxf(fabsf(in[6]), fabsf(in[7])));
    float amax = fmaxf(a0, a1);
    // reduce across the 4 threads of this 32-block (quad is wave-aligned)
    amax = fmaxf(amax, __shfl_xor(amax, 1));
    amax = fmaxf(amax, __shfl_xor(amax, 2));
    amax = fmaxf(amax, 1e-12f);

    // scale = float(fp16(amax/6)) exactly like the reference
    float scale = (float)(_Float16)(amax / 6.0f);
    float sdiv  = fmaxf(scale, 1e-12f);

    union { _Float16 h[8]; uint4 v; } o;
#pragma unroll
    for (int i = 0; i < 8; ++i) {
        float xn = in[i] / sdiv;              // IEEE div, matches ref
        float s  = snap_mxfp4(fabsf(xn));
        o.h[i]   = (_Float16)copysignf(s * scale, xn);  // s*scale exact in f32
    }
    *(uint4*)(xq + base) = o.v;
}

// ------------------------------ W -> fp16 ----------------------------------

__global__ __launch_bounds__(256) void conv_w_kernel(
        const float* __restrict__ W, _Float16* __restrict__ Wq) {
    size_t t    = (size_t)blockIdx.x * 256 + threadIdx.x;
    size_t base = t * 8;
    const float4* p = (const float4*)(W + base);
    float4 v0 = p[0];
    float4 v1 = p[1];
    float in[8] = {v0.x, v0.y, v0.z, v0.w, v1.x, v1.y, v1.z, v1.w};
    union { _Float16 h[8]; uint4 v; } o;
#pragma unroll
    for (int i = 0; i < 8; ++i) o.h[i] = (_Float16)in[i];
    *(uint4*)(Wq + base) = o.v;
}

// -------------------------------- GEMM -------------------------------------
// C[m][n] = sum_k A[m][k] * B[n][k] + bias[n]   (A = x_q, B = W, both K-major)
// Block: 128x128 output, 256 threads = 4 waves in 2x2, each wave 4x4 MFMA
// tiles of 16x16.  K-tile = 32.  LDS staged via global_load_lds width=16.
// LDS layout is chunk-linear (16B chunks in lane order, required by
// global_load_lds wave-uniform-base semantics); K-chunk position is
// XOR-swizzled (kc' = kc ^ (row&3)) so ds_read_b128 fragment reads are
// <=2-way bank aliased (free per m136).

#define BM 128
#define BN 128
#define BK 32

__global__ __launch_bounds__(256) void gemm_f16_kernel(
        const _Float16* __restrict__ A, const _Float16* __restrict__ B,
        const float* __restrict__ bias, float* __restrict__ C) {
    __shared__ __align__(16) _Float16 sA[BM * BK];
    __shared__ __align__(16) _Float16 sB[BN * BK];

    const int tid   = threadIdx.x;
    const int lane  = tid & 63;
    const int wave  = tid >> 6;
    const int wr    = wave >> 1;   // wave row (0..1)
    const int wc    = wave & 1;    // wave col (0..1)
    const int mlane = lane & 15;
    const int kq    = lane >> 4;   // 0..3: which 8-wide K chunk

    const int rowStart = blockIdx.y * BM;
    const int colStart = blockIdx.x * BN;

    // Staging: 512 16B-chunks per tile; thread feeds chunks p0=tid, p1=tid+256.
    // LDS chunk p holds global (row=p>>2, kc_src=(p&3)^(row&3)).
    const int p0 = tid, p1 = tid + 256;
    const int r0 = p0 >> 2, r1 = p1 >> 2;
    const int kc0 = (p0 & 3) ^ (r0 & 3);
    const int kc1 = (p1 & 3) ^ (r1 & 3);
    const _Float16* aSrc0 = A + (size_t)(rowStart + r0) * K_DIM + kc0 * 8;
    const _Float16* aSrc1 = A + (size_t)(rowStart + r1) * K_DIM + kc1 * 8;
    const _Float16* bSrc0 = B + (size_t)(colStart + r0) * K_DIM + kc0 * 8;
    const _Float16* bSrc1 = B + (size_t)(colStart + r1) * K_DIM + kc1 * 8;

    // wave-uniform LDS bases; HW adds lane*16B
    _Float16* ldsA0 = sA + (wave * 64) * 8;
    _Float16* ldsA1 = sA + (256 + wave * 64) * 8;
    _Float16* ldsB0 = sB + (wave * 64) * 8;
    _Float16* ldsB1 = sB + (256 + wave * 64) * 8;

    // Fragment LDS offsets (in halfs). A-operand: m=lane&15, k=kq*8+j.
    int aOff[4], bOff[4];
#pragma unroll
    for (int i = 0; i < 4; ++i) {
        int row = wr * 64 + i * 16 + mlane;
        aOff[i] = (row * 4 + (kq ^ (row & 3))) * 8;
        int col = wc * 64 + i * 16 + mlane;
        bOff[i] = (col * 4 + (kq ^ (col & 3))) * 8;
    }

    floatx4 acc[4][4];
    const floatx4 z4 = {0.f, 0.f, 0.f, 0.f};
#pragma unroll
    for (int i = 0; i < 4; ++i)
#pragma unroll
        for (int j = 0; j < 4; ++j) acc[i][j] = z4;

    for (int k0 = 0; k0 < K_DIM; k0 += BK) {
        __builtin_amdgcn_global_load_lds(
            (const __attribute__((address_space(1))) unsigned int*)(const void*)(aSrc0 + k0),
            (__attribute__((address_space(3))) unsigned int*)(void*)ldsA0, 16, 0, 0);
        __builtin_amdgcn_global_load_lds(
            (const __attribute__((address_space(1))) unsigned int*)(const void*)(aSrc1 + k0),
            (__attribute__((address_space(3))) unsigned int*)(void*)ldsA1, 16, 0, 0);
        __builtin_amdgcn_global_load_lds(
            (const __attribute__((address_space(1))) unsigned int*)(const void*)(bSrc0 + k0),
            (__attribute__((address_space(3))) unsigned int*)(void*)ldsB0, 16, 0, 0);
        __builtin_amdgcn_global_load_lds(
            (const __attribute__((address_space(1))) unsigned int*)(const void*)(bSrc1 + k0),
            (__attribute__((address_space(3))) unsigned int*)(void*)ldsB1, 16, 0, 0);

        __syncthreads();   // drains vmcnt: LDS tiles complete

        half8 af[4], bf[4];
#pragma unroll
        for (int i = 0; i < 4; ++i) {
            af[i] = *(const half8*)(sA + aOff[i]);
            bf[i] = *(const half8*)(sB + bOff[i]);
        }
#pragma unroll
        for (int mt = 0; mt < 4; ++mt)
#pragma unroll
            for (int nt = 0; nt < 4; ++nt)
                acc[mt][nt] = __builtin_amdgcn_mfma_f32_16x16x32_f16(
                    af[mt], bf[nt], acc[mt][nt], 0, 0, 0);

        __syncthreads();   // all reads done before next overwrite
    }

    // Epilogue. C/D layout: col = lane&15, row = (lane>>4)*4 + reg.
#pragma unroll
    for (int mt = 0; mt < 4; ++mt) {
        int gm = rowStart + wr * 64 + mt * 16 + kq * 4;
#pragma unroll
        for (int nt = 0; nt < 4; ++nt) {
            int gn = colStart + wc * 64 + nt * 16 + mlane;
            float bv = bias[gn];
#pragma unroll
            for (int r = 0; r < 4; ++r)
                C[(size_t)(gm + r) * N_DIM + gn] = acc[mt][nt][r] + bv;
        }
    }
}

// ------------------------------- launch ------------------------------------

extern "C" void kernel_launch(void* const* d_in, const int* in_sizes, int n_in,
                              void* d_out, int out_size, void* d_ws, size_t ws_size,
                              hipStream_t stream) {
    const float* x    = (const float*)d_in[0];   // [2,4096,4096]
    const float* W    = (const float*)d_in[1];   // [11008,4096]
    const float* bias = (const float*)d_in[2];   // [11008]
    float* out = (float*)d_out;                  // [2,4096,11008]

    _Float16* Aq = (_Float16*)d_ws;                          // 8192*4096 halfs = 64MB
    _Float16* Wq = Aq + (size_t)M_DIM * K_DIM;               // 11008*4096 halfs = 86MB

    // quant: 33554432 elems / 8 per thread / 256 per block
    quant_x_kernel<<<16384, 256, 0, stream>>>(x, Aq);
    // W convert: 45088768 elems / 8 / 256
    conv_w_kernel<<<22016, 256, 0, stream>>>(W, Wq);
    // GEMM: grid (N/128, M/128)
    gemm_f16_kernel<<<dim3(N_DIM / BN, M_DIM / BM), 256, 0, stream>>>(Aq, Wq, bias, out);
}

// Round 2
// 1457.664 us; speedup vs baseline: 1.0119x; 1.0119x over previous
//
#include <hip/hip_runtime.h>

// ---------------------------------------------------------------------------
// MixedFPQuantizedLinear: per-32-block MXFP4 quant of x (fp16 scale) then
// C = x_q @ W^T + bias.  M=8192, K=4096, N=11008, all fp32 in/out.
// R2: (a) K-loop reordered so global_load_lds(k+1) issues before the MFMA
//     phase (latency hidden behind compute instead of exposed at barrier),
//     (b) N-band grid swizzle for L3 locality (FETCH 3GB -> ~0.3GB),
//     (c) quant+conv fused into one launch (kills ~300us of gap/serial time).
// ---------------------------------------------------------------------------

#define M_DIM 8192
#define K_DIM 4096
#define N_DIM 11008

typedef float floatx4 __attribute__((ext_vector_type(4)));
typedef _Float16 half8 __attribute__((ext_vector_type(8)));

// ----------------------- fused quant(x) + convert(W) -----------------------

__device__ inline float snap_mxfp4(float a) {
    // grid {0,0.5,1,1.5,2,3,4,6}; ties go to LOWER value (matches ref).
    float lo  = (a <= 0.25f) ? 0.0f : ((a <= 0.75f) ? 0.5f : 1.0f);
    float mid = (a <= 1.75f) ? 1.5f : 2.0f;
    float hi  = (a <= 3.5f)  ? 3.0f : ((a <= 5.0f) ? 4.0f : 6.0f);
    return (a <= 1.25f) ? lo : ((a <= 2.5f) ? mid : hi);
}

#define QUANT_BLOCKS 16384   // 2*4096*4096 / (8*256)
#define CONV_BLOCKS  22016   // 11008*4096 / (8*256)

__global__ __launch_bounds__(256) void prep_kernel(
        const float* __restrict__ x, _Float16* __restrict__ xq,
        const float* __restrict__ W, _Float16* __restrict__ wq) {
    if (blockIdx.x < QUANT_BLOCKS) {
        size_t t    = (size_t)blockIdx.x * 256 + threadIdx.x;
        size_t base = t * 8;
        const float4* p = (const float4*)(x + base);
        float4 v0 = p[0];
        float4 v1 = p[1];
        float in[8] = {v0.x, v0.y, v0.z, v0.w, v1.x, v1.y, v1.z, v1.w};

        float a0 = fmaxf(fmaxf(fabsf(in[0]), fabsf(in[1])), fmaxf(fabsf(in[2]), fabsf(in[3])));
        float a1 = fmaxf(fmaxf(fabsf(in[4]), fabsf(in[5])), fmaxf(fabsf(in[6]), fabsf(in[7])));
        float amax = fmaxf(a0, a1);
        amax = fmaxf(amax, __shfl_xor(amax, 1));
        amax = fmaxf(amax, __shfl_xor(amax, 2));
        amax = fmaxf(amax, 1e-12f);

        float scale = (float)(_Float16)(amax / 6.0f);   // fp16 round-trip like ref
        float sdiv  = fmaxf(scale, 1e-12f);

        union { _Float16 h[8]; uint4 v; } o;
#pragma unroll
        for (int i = 0; i < 8; ++i) {
            float xn = in[i] / sdiv;
            float s  = snap_mxfp4(fabsf(xn));
            o.h[i]   = (_Float16)copysignf(s * scale, xn);
        }
        *(uint4*)(xq + base) = o.v;
    } else {
        size_t t    = (size_t)(blockIdx.x - QUANT_BLOCKS) * 256 + threadIdx.x;
        size_t base = t * 8;
        const float4* p = (const float4*)(W + base);
        float4 v0 = p[0];
        float4 v1 = p[1];
        float in[8] = {v0.x, v0.y, v0.z, v0.w, v1.x, v1.y, v1.z, v1.w};
        union { _Float16 h[8]; uint4 v; } o;
#pragma unroll
        for (int i = 0; i < 8; ++i) o.h[i] = (_Float16)in[i];
        *(uint4*)(wq + base) = o.v;
    }
}

// -------------------------------- GEMM -------------------------------------
// C[m][n] = sum_k A[m][k] * B[n][k] + bias[n]   (A = x_q, B = W, both K-major)
// 128x128 block, 256 threads = 4 waves (2x2), wave does 4x4 16x16x32 MFMAs.
// K-tile 32.  LDS chunk-linear (global_load_lds wave-uniform base), K-chunk
// XOR-swizzled (kc' = kc ^ (row&3)).
// K-loop order per iter:  barrier(drain tile k) -> ds_read frags ->
// barrier(lgkm only, cheap) -> issue loads k+1 -> MFMA (covers latency).

#define BM 128
#define BN 128
#define BK 32
#define M_TILES 64
#define N_TILES 86
#define BANDW 32          // N-tiles per L3 band; bands of 64*32=2048 blocks

__global__ __launch_bounds__(256) void gemm_f16_kernel(
        const _Float16* __restrict__ A, const _Float16* __restrict__ B,
        const float* __restrict__ bias, float* __restrict__ C) {
    __shared__ __align__(16) _Float16 sA[BM * BK];
    __shared__ __align__(16) _Float16 sB[BN * BK];

    const int tid   = threadIdx.x;
    const int lane  = tid & 63;
    const int wave  = tid >> 6;
    const int wr    = wave >> 1;
    const int wc    = wave & 1;
    const int mlane = lane & 15;
    const int kq    = lane >> 4;

    // --- L3-locality swizzle: bands of BANDW n-tiles, n fastest within band.
    int pid = blockIdx.x;
    int mTile, nTile;
    if (pid < M_TILES * BANDW * 2) {              // bands 0,1 (width 32)
        int band = pid >> 11;                     // /2048
        int rem  = pid & 2047;
        nTile = (band << 5) + (rem & 31);
        mTile = rem >> 5;
    } else {                                      // band 2 (width 86-64=22)
        int rem = pid - M_TILES * BANDW * 2;
        nTile = 64 + rem % 22;
        mTile = rem / 22;
    }
    const int rowStart = mTile * BM;
    const int colStart = nTile * BN;

    // Staging: 512 16B-chunks per tile; thread feeds chunks p0=tid, p1=tid+256.
    const int p0 = tid, p1 = tid + 256;
    const int r0 = p0 >> 2, r1 = p1 >> 2;
    const int kc0 = (p0 & 3) ^ (r0 & 3);
    const int kc1 = (p1 & 3) ^ (r1 & 3);
    const _Float16* aSrc0 = A + (size_t)(rowStart + r0) * K_DIM + kc0 * 8;
    const _Float16* aSrc1 = A + (size_t)(rowStart + r1) * K_DIM + kc1 * 8;
    const _Float16* bSrc0 = B + (size_t)(colStart + r0) * K_DIM + kc0 * 8;
    const _Float16* bSrc1 = B + (size_t)(colStart + r1) * K_DIM + kc1 * 8;

    _Float16* ldsA0 = sA + (wave * 64) * 8;
    _Float16* ldsA1 = sA + (256 + wave * 64) * 8;
    _Float16* ldsB0 = sB + (wave * 64) * 8;
    _Float16* ldsB1 = sB + (256 + wave * 64) * 8;

    int aOff[4], bOff[4];
#pragma unroll
    for (int i = 0; i < 4; ++i) {
        int row = wr * 64 + i * 16 + mlane;
        aOff[i] = (row * 4 + (kq ^ (row & 3))) * 8;
        int col = wc * 64 + i * 16 + mlane;
        bOff[i] = (col * 4 + (kq ^ (col & 3))) * 8;
    }

    floatx4 acc[4][4];
    const floatx4 z4 = {0.f, 0.f, 0.f, 0.f};
#pragma unroll
    for (int i = 0; i < 4; ++i)
#pragma unroll
        for (int j = 0; j < 4; ++j) acc[i][j] = z4;

#define ISSUE_LOADS(K0)                                                            \
    do {                                                                           \
        __builtin_amdgcn_global_load_lds(                                          \
            (const __attribute__((address_space(1))) unsigned int*)(const void*)(aSrc0 + (K0)), \
            (__attribute__((address_space(3))) unsigned int*)(void*)ldsA0, 16, 0, 0); \
        __builtin_amdgcn_global_load_lds(                                          \
            (const __attribute__((address_space(1))) unsigned int*)(const void*)(aSrc1 + (K0)), \
            (__attribute__((address_space(3))) unsigned int*)(void*)ldsA1, 16, 0, 0); \
        __builtin_amdgcn_global_load_lds(                                          \
            (const __attribute__((address_space(1))) unsigned int*)(const void*)(bSrc0 + (K0)), \
            (__attribute__((address_space(3))) unsigned int*)(void*)ldsB0, 16, 0, 0); \
        __builtin_amdgcn_global_load_lds(                                          \
            (const __attribute__((address_space(1))) unsigned int*)(const void*)(bSrc1 + (K0)), \
            (__attribute__((address_space(3))) unsigned int*)(void*)ldsB1, 16, 0, 0); \
    } while (0)

    ISSUE_LOADS(0);   // prologue

    for (int k0 = 0; k0 < K_DIM; k0 += BK) {
        __syncthreads();   // tile-k loads complete (the vmcnt drain)

        half8 af[4], bf[4];
#pragma unroll
        for (int i = 0; i < 4; ++i) {
            af[i] = *(const half8*)(sA + aOff[i]);
            bf[i] = *(const half8*)(sB + bOff[i]);
        }

        __syncthreads();   // all waves' ds_reads done; vmcnt already 0 -> cheap

        if (k0 + BK < K_DIM) ISSUE_LOADS(k0 + BK);   // in flight during MFMA

#pragma unroll
        for (int mt = 0; mt < 4; ++mt)
#pragma unroll
            for (int nt = 0; nt < 4; ++nt)
                acc[mt][nt] = __builtin_amdgcn_mfma_f32_16x16x32_f16(
                    af[mt], bf[nt], acc[mt][nt], 0, 0, 0);
    }

    // Epilogue. C/D layout: col = lane&15, row = (lane>>4)*4 + reg.
#pragma unroll
    for (int mt = 0; mt < 4; ++mt) {
        int gm = rowStart + wr * 64 + mt * 16 + kq * 4;
#pragma unroll
        for (int nt = 0; nt < 4; ++nt) {
            int gn = colStart + wc * 64 + nt * 16 + mlane;
            float bv = bias[gn];
#pragma unroll
            for (int r = 0; r < 4; ++r)
                C[(size_t)(gm + r) * N_DIM + gn] = acc[mt][nt][r] + bv;
        }
    }
}

// ------------------------------- launch ------------------------------------

extern "C" void kernel_launch(void* const* d_in, const int* in_sizes, int n_in,
                              void* d_out, int out_size, void* d_ws, size_t ws_size,
                              hipStream_t stream) {
    const float* x    = (const float*)d_in[0];   // [2,4096,4096]
    const float* W    = (const float*)d_in[1];   // [11008,4096]
    const float* bias = (const float*)d_in[2];   // [11008]
    float* out = (float*)d_out;                  // [2,4096,11008]

    _Float16* Aq = (_Float16*)d_ws;                          // 64MB
    _Float16* Wq = Aq + (size_t)M_DIM * K_DIM;               // 86MB

    prep_kernel<<<QUANT_BLOCKS + CONV_BLOCKS, 256, 0, stream>>>(x, Aq, W, Wq);
    gemm_f16_kernel<<<M_TILES * N_TILES, 256, 0, stream>>>(Aq, Wq, bias, out);
}